// Round 7
// baseline (563.910 us; speedup 1.0000x reference)
//
#include <hip/hip_runtime.h>
#include <hip/hip_bf16.h>

// Matryoshka linear: y[m][n] = sum_k x[m][k] * W_seg[n_local][k]
//   seg0: n in [0,1024),    K=1024   seg1: n in [1024,2048), K=2048
//   seg2: n in [2048,4096), K=4096   M = 16384, out [16384][4096] f32
//
// Round 7: faithful m201 8-phase port. BK=64, 4 phases per K-tile:
//   p1 (mh0,kh0): 4 A + 4 B ds_read || stage A-kh0(t+1)
//   p2 (mh1,kh0): 4 A           || stage B-kh0(t+1), vmcnt(4)
//   p3 (mh0,kh1): 4 A + 4 B     || stage A-kh1(t+1)
//   p4 (mh1,kh1): 4 A           || stage B-kh1(t+1), vmcnt(4)
// each phase: reads+stage -> s_barrier -> lgkmcnt(0) -> setprio(1)
// 16 MFMA setprio(0) -> [vmcnt(4) at p2/p4] -> s_barrier.
// vmcnt audit (steady state, 2 gloads/phase, q1..q8 per tile):
//   p2-end vmcnt(4): drains prev tile's q5-q8 = kh1(t) -> ready for p3  OK
//   p4-end vmcnt(4): drains this tile's q1-q4 = kh0(t+1) -> ready p1    OK
// Slot write races: stage(t+1) unit targets slot holding t-1's unit,
// whose last read completed before t-1's closing barrier.              OK
// Slots are 256x32 bf16 = r3's exact geometry: verified 0-conflict
// XOR swizzle + staging formulas reused verbatim.

typedef short bf16x8 __attribute__((ext_vector_type(8)));
typedef float f32x4 __attribute__((ext_vector_type(4)));

__device__ __forceinline__ ushort f2bf(float f) {
  union { float f; unsigned u; } c; c.f = f;
  unsigned u = c.u;
  unsigned r = u + 0x7fffu + ((u >> 16) & 1u);  // RNE
  return (ushort)(r >> 16);
}

// One fused convert: dst (bf16) is contiguous in ws = [x | W0 | W1 | W2].
__global__ void cvt_all_bf16(const float* __restrict__ x,
                             const float* __restrict__ W0,
                             const float* __restrict__ W1,
                             const float* __restrict__ W2,
                             ushort* __restrict__ dst) {
  const int X4  = 16777216;             // xN/4
  const int E0  = X4 + 262144;          // + w0N/4
  const int E1  = E0 + 524288;          // + w1N/4
  const int E2  = E1 + 2097152;         // + w2N/4 (total float4 count)
  int i = blockIdx.x * blockDim.x + threadIdx.x;
  int stride = gridDim.x * blockDim.x;
  ushort4* out4 = (ushort4*)dst;
  for (int j = i; j < E2; j += stride) {
    const float4* src;
    if (j < X4)      src = (const float4*)x  + j;
    else if (j < E0) src = (const float4*)W0 + (j - X4);
    else if (j < E1) src = (const float4*)W1 + (j - E0);
    else             src = (const float4*)W2 + (j - E1);
    float4 v = *src;
    ushort4 o;
    o.x = f2bf(v.x); o.y = f2bf(v.y); o.z = f2bf(v.z); o.w = f2bf(v.w);
    out4[j] = o;
  }
}

__device__ __forceinline__ void gload16(const ushort* g, const ushort* l) {
  __builtin_amdgcn_global_load_lds(
      (const __attribute__((address_space(1))) void*)g,
      (__attribute__((address_space(3))) void*)l, 16, 0, 0);
}

#define MF(av, bv, mi, ni) \
  acc[mi][ni] = __builtin_amdgcn_mfma_f32_16x16x32_bf16(av, bv, acc[mi][ni], 0, 0, 0)

#define MFQ0(A0, A1, A2, A3) \
  MF(A0, b0, 0, 0); MF(A0, b1, 0, 1); MF(A0, b2, 0, 2); MF(A0, b3, 0, 3); \
  MF(A1, b0, 1, 0); MF(A1, b1, 1, 1); MF(A1, b2, 1, 2); MF(A1, b3, 1, 3); \
  MF(A2, b0, 2, 0); MF(A2, b1, 2, 1); MF(A2, b2, 2, 2); MF(A2, b3, 2, 3); \
  MF(A3, b0, 3, 0); MF(A3, b1, 3, 1); MF(A3, b2, 3, 2); MF(A3, b3, 3, 3)

#define MFQ1(A0, A1, A2, A3) \
  MF(A0, b0, 4, 0); MF(A0, b1, 4, 1); MF(A0, b2, 4, 2); MF(A0, b3, 4, 3); \
  MF(A1, b0, 5, 0); MF(A1, b1, 5, 1); MF(A1, b2, 5, 2); MF(A1, b3, 5, 3); \
  MF(A2, b0, 6, 0); MF(A2, b1, 6, 1); MF(A2, b2, 6, 2); MF(A2, b3, 6, 3); \
  MF(A3, b0, 7, 0); MF(A3, b1, 7, 1); MF(A3, b2, 7, 2); MF(A3, b3, 7, 3)

__global__ __launch_bounds__(512, 2) void matry_gemm(
    const ushort* __restrict__ xbf,   // [16384][4096] bf16
    const ushort* __restrict__ w0,    // [1024][1024]
    const ushort* __restrict__ w1,    // [1024][2048]
    const ushort* __restrict__ w2,    // [2048][4096]
    float* __restrict__ out) {        // [16384][4096] f32
  // 4 units (A-kh0, A-kh1, B-kh0, B-kh1) x 2 slots x 16KB = 128KB
  __shared__ __align__(16) ushort sA0[2][8192];
  __shared__ __align__(16) ushort sA1[2][8192];
  __shared__ __align__(16) ushort sB0[2][8192];
  __shared__ __align__(16) ushort sB1[2][8192];

  const int bid = blockIdx.x;
  const int rt = bid & 63;    // identical mapping to round 3
  const int ct = bid >> 6;

  int K; const ushort* W; int nl0;
  if (ct < 4)      { K = 1024; W = w0; nl0 = ct * 256; }
  else if (ct < 8) { K = 2048; W = w1; nl0 = (ct - 4) * 256; }
  else             { K = 4096; W = w2; nl0 = (ct - 8) * 256; }
  const int NT = K >> 6;          // K-tiles of 64: 16/32/64
  const int m0 = rt * 256;
  const int n0 = ct * 256;

  const int tid  = threadIdx.x;
  const int wid  = tid >> 6;
  const int lane = tid & 63;
  const int wm = wid >> 2;        // 0..1
  const int wn = wid & 3;         // 0..3
  const int fr = lane & 15;
  const int swz_e = (((lane >> 4) ^ ((lane >> 1) & 3)) << 3);  // r3, 0-conf

  // per-lane ds_read bases (elements within a slot)
  const int aoff = (wm * 128 + fr) * 32 + swz_e;  // + (mh*64+mi*16)*32
  const int boff = (wn * 64 + fr) * 32 + swz_e;   // + ni*512

  // staging (r3 formulas verbatim; slot = 256 rows x 32 k)
  const int srow = tid >> 2;                                   // 0..127
  const int scol = (((tid & 3) ^ ((tid >> 3) & 3)) << 3);
  const ushort* Ag = xbf + (size_t)(m0 + srow) * 4096 + scol;
  const ushort* Bg = W + (size_t)(nl0 + srow) * K + scol;
  const size_t Ac1 = (size_t)128 * 4096;   // chunk1 = rows 128..255
  const size_t Bc1 = (size_t)128 * K;
  const int dst0 = tid * 8, dst1 = 4096 + tid * 8;

  f32x4 acc[8][4];
#pragma unroll
  for (int mi = 0; mi < 8; ++mi)
#pragma unroll
    for (int ni = 0; ni < 4; ++ni)
      acc[mi][ni] = (f32x4){0.f, 0.f, 0.f, 0.f};

  // ---- prologue: stage tile 0 (q1..q4 = kh0 A,B; q5..q8 = kh1 A,B) ----
  gload16(Ag, &sA0[0][dst0]);
  gload16(Ag + Ac1, &sA0[0][dst1]);
  gload16(Bg, &sB0[0][dst0]);
  gload16(Bg + Bc1, &sB0[0][dst1]);
  gload16(Ag + 32, &sA1[0][dst0]);
  gload16(Ag + Ac1 + 32, &sA1[0][dst1]);
  gload16(Bg + 32, &sB1[0][dst0]);
  gload16(Bg + Bc1 + 32, &sB1[0][dst1]);
  asm volatile("s_waitcnt vmcnt(4)" ::: "memory");  // kh0(0) landed
  __builtin_amdgcn_s_barrier();

  // ---- main loop: 1 K-tile(64) per iter, 4 phases ----
  for (int t = 0; t < NT; ++t) {
    const int cur = t & 1, nb = cur ^ 1;
    const ushort* a0p = &sA0[cur][aoff];
    const ushort* a1p = &sA1[cur][aoff];
    const ushort* b0p = &sB0[cur][boff];
    const ushort* b1p = &sB1[cur][boff];
    const int tk = (t + 1 < NT) ? (t + 1) : (NT - 1);  // clamped tail
    const size_t kg = (size_t)tk * 64;

    bf16x8 a0, a1, a2, a3, b0, b1, b2, b3;

    // ---- p1 (mh0, kh0): 8 reads || stage A-kh0(t+1) ----
    a0 = *(const bf16x8*)(a0p);
    a1 = *(const bf16x8*)(a0p + 512);
    a2 = *(const bf16x8*)(a0p + 1024);
    a3 = *(const bf16x8*)(a0p + 1536);
    b0 = *(const bf16x8*)(b0p);
    b1 = *(const bf16x8*)(b0p + 512);
    b2 = *(const bf16x8*)(b0p + 1024);
    b3 = *(const bf16x8*)(b0p + 1536);
    gload16(Ag + kg, &sA0[nb][dst0]);
    gload16(Ag + Ac1 + kg, &sA0[nb][dst1]);
    __builtin_amdgcn_s_barrier();
    asm volatile("s_waitcnt lgkmcnt(0)" ::: "memory");
    __builtin_amdgcn_s_setprio(1);
    MFQ0(a0, a1, a2, a3);
    __builtin_amdgcn_s_setprio(0);
    __builtin_amdgcn_s_barrier();

    // ---- p2 (mh1, kh0): 4 reads || stage B-kh0(t+1) ----
    a0 = *(const bf16x8*)(a0p + 2048);
    a1 = *(const bf16x8*)(a0p + 2560);
    a2 = *(const bf16x8*)(a0p + 3072);
    a3 = *(const bf16x8*)(a0p + 3584);
    gload16(Bg + kg, &sB0[nb][dst0]);
    gload16(Bg + Bc1 + kg, &sB0[nb][dst1]);
    __builtin_amdgcn_s_barrier();
    asm volatile("s_waitcnt lgkmcnt(0)" ::: "memory");
    __builtin_amdgcn_s_setprio(1);
    MFQ1(a0, a1, a2, a3);
    __builtin_amdgcn_s_setprio(0);
    asm volatile("s_waitcnt vmcnt(4)" ::: "memory");  // kh1(t) landed
    __builtin_amdgcn_s_barrier();

    // ---- p3 (mh0, kh1): 8 reads || stage A-kh1(t+1) ----
    a0 = *(const bf16x8*)(a1p);
    a1 = *(const bf16x8*)(a1p + 512);
    a2 = *(const bf16x8*)(a1p + 1024);
    a3 = *(const bf16x8*)(a1p + 1536);
    b0 = *(const bf16x8*)(b1p);
    b1 = *(const bf16x8*)(b1p + 512);
    b2 = *(const bf16x8*)(b1p + 1024);
    b3 = *(const bf16x8*)(b1p + 1536);
    gload16(Ag + kg + 32, &sA1[nb][dst0]);
    gload16(Ag + Ac1 + kg + 32, &sA1[nb][dst1]);
    __builtin_amdgcn_s_barrier();
    asm volatile("s_waitcnt lgkmcnt(0)" ::: "memory");
    __builtin_amdgcn_s_setprio(1);
    MFQ0(a0, a1, a2, a3);
    __builtin_amdgcn_s_setprio(0);
    __builtin_amdgcn_s_barrier();

    // ---- p4 (mh1, kh1): 4 reads || stage B-kh1(t+1) ----
    a0 = *(const bf16x8*)(a1p + 2048);
    a1 = *(const bf16x8*)(a1p + 2560);
    a2 = *(const bf16x8*)(a1p + 3072);
    a3 = *(const bf16x8*)(a1p + 3584);
    gload16(Bg + kg + 32, &sB1[nb][dst0]);
    gload16(Bg + Bc1 + kg + 32, &sB1[nb][dst1]);
    __builtin_amdgcn_s_barrier();
    asm volatile("s_waitcnt lgkmcnt(0)" ::: "memory");
    __builtin_amdgcn_s_setprio(1);
    MFQ1(a0, a1, a2, a3);
    __builtin_amdgcn_s_setprio(0);
    asm volatile("s_waitcnt vmcnt(4)" ::: "memory");  // kh0(t+1) landed
    __builtin_amdgcn_s_barrier();
  }

  // ---- epilogue: C/D layout col=lane&15, row=(lane>>4)*4+reg [m89] ----
  const int rq = (lane >> 4) * 4;
#pragma unroll
  for (int mi = 0; mi < 8; ++mi) {
#pragma unroll
    for (int ni = 0; ni < 4; ++ni) {
      const int n = n0 + wn * 64 + ni * 16 + fr;
#pragma unroll
      for (int r = 0; r < 4; ++r) {
        const int m = m0 + wm * 128 + mi * 16 + rq + r;
        out[(size_t)m * 4096 + n] = acc[mi][ni][r];
      }
    }
  }
}

// Correct-but-slow fallback if workspace is too small.
__global__ void naive_kernel(const float* __restrict__ x,
                             const float* __restrict__ W0,
                             const float* __restrict__ W1,
                             const float* __restrict__ W2,
                             float* __restrict__ out) {
  long idx = (long)blockIdx.x * 256 + threadIdx.x;
  int n = (int)(idx & 4095);
  long m = idx >> 12;
  int K; const float* W; int nl;
  if (n < 1024)      { K = 1024; W = W0; nl = n; }
  else if (n < 2048) { K = 2048; W = W1; nl = n - 1024; }
  else               { K = 4096; W = W2; nl = n - 2048; }
  const float* xr = x + m * 4096;
  const float* wr = W + (long)nl * K;
  float s = 0.f;
  for (int k = 0; k < K; ++k) s += xr[k] * wr[k];
  out[idx] = s;
}

extern "C" void kernel_launch(void* const* d_in, const int* in_sizes, int n_in,
                              void* d_out, int out_size, void* d_ws,
                              size_t ws_size, hipStream_t stream) {
  const float* x  = (const float*)d_in[0];
  const float* W0 = (const float*)d_in[1];
  const float* W1 = (const float*)d_in[2];
  const float* W2 = (const float*)d_in[3];
  float* out = (float*)d_out;

  const size_t xN  = (size_t)16384 * 4096;
  const size_t w0N = (size_t)1024 * 1024;
  const size_t w1N = (size_t)1024 * 2048;
  const size_t w2N = (size_t)2048 * 4096;
  const size_t need = (xN + w0N + w1N + w2N) * sizeof(ushort);  // ~150 MB

  if (ws_size >= need) {
    ushort* xbf = (ushort*)d_ws;
    ushort* w0b = xbf + xN;
    ushort* w1b = w0b + w0N;
    ushort* w2b = w1b + w1N;
    cvt_all_bf16<<<4096, 256, 0, stream>>>(x, W0, W1, W2, xbf);
    // grid: 64 row-tiles (fast) x 16 col-tiles (slow)
    matry_gemm<<<1024, 512, 0, stream>>>(xbf, w0b, w1b, w2b, out);
  } else {
    naive_kernel<<<(int)((xN + 255) / 256), 256, 0, stream>>>(x, W0, W1, W2, out);
  }
}